// Round 13
// baseline (134.990 us; speedup 1.0000x reference)
//
#include <hip/hip_runtime.h>
#include <hip/hip_bf16.h>
#include <stdint.h>

// out[b,s,d] = sum_t w[b,s,t] * x[b,t,d]
//   w = softmax(uniform(key=42, (4,4096,4096), -0.1, 0.1), -1) / 4   (denom
//   = sum_{b,t} softmax = B = 4 exactly; verified rounds 2-11).
// PRNG (verified): JAX partitionable threefry, counter (0, flat_idx),
// key (0,42), draw = x0 ^ x1.
// Round 13: producer/consumer wave specialization. Rounds 9-12 showed the
// register allocator compresses to 32 VGPRs and sinks B-loads into the MFMA
// phase (latency exposed; real VALU issue ~44%, the 87% VALUBusy is a
// gfx94x x4-formula artifact). Fix: 4 producer waves = pure VALU threefry ->
// LDS ring (no loads -> nothing to sink); 4 consumer waves = loads + MFMA
// (never critical). r11 math kept verbatim; r12's unproven changes reverted.

#define S_ 4096
#define D_ 64

#define EXP_A32 ((float)(0.2 * 1.4426950408889634 / 4294967296.0)) // 0.2*log2e*2^-32
#define EXP_B   ((float)(-0.1 * 1.4426950408889634))               // -0.1*log2e

typedef __attribute__((ext_vector_type(8))) short short8v;   // 8 bf16 = 4 VGPR
typedef __attribute__((ext_vector_type(4))) float floatx4;

// 8 partitionable-threefry chains, interleaved round-by-round (r11 verbatim).
// Counters (0, c0+i) i=0..7, key (0,42); draw = x0 ^ x1.
__device__ __forceinline__ void tf8(uint32_t c0, uint32_t r[8]) {
    const uint32_t k1 = 42u, k2 = 0x1BD11BDAu ^ 42u;
    uint32_t a[8], b[8];
#pragma unroll
    for (int i = 0; i < 8; ++i) { a[i] = 0u; b[i] = c0 + (uint32_t)i + k1; }
#define TF_RND(rot)                                          \
    _Pragma("unroll")                                        \
    for (int i = 0; i < 8; ++i) {                            \
        a[i] += b[i];                                        \
        b[i] = __builtin_rotateleft32(b[i], (rot));          \
        b[i] ^= a[i];                                        \
    }
#define TF_INJ(ka, kb)                                       \
    _Pragma("unroll")                                        \
    for (int i = 0; i < 8; ++i) { a[i] += (ka); b[i] += (kb); }
    TF_RND(13) TF_RND(15) TF_RND(26) TF_RND(6)
    TF_INJ(k1, k2 + 1u)
    TF_RND(17) TF_RND(29) TF_RND(16) TF_RND(24)
    TF_INJ(k2, 2u)
    TF_RND(13) TF_RND(15) TF_RND(26) TF_RND(6)
    TF_INJ(0u, k1 + 3u)
    TF_RND(17) TF_RND(29) TF_RND(16) TF_RND(24)
    TF_INJ(k1, k2 + 4u)
    TF_RND(13) TF_RND(15) TF_RND(26) TF_RND(6)
    TF_INJ(k2, 5u)
#undef TF_RND
#undef TF_INJ
#pragma unroll
    for (int i = 0; i < 8; ++i) r[i] = a[i] ^ b[i];
}

// packed pair {lo: bf16(e0), hi: bf16(e1)}, RNE, single instruction
__device__ __forceinline__ uint32_t cvt_pk_bf16(float e0, float e1) {
    uint32_t r;
    asm("v_cvt_pk_bf16_f32 %0, %1, %2" : "=v"(r) : "v"(e0), "v"(e1));
    return r;
}

// 8 consecutive exp-weights (counters c0..c0+7) -> bf16x8 A-fragment.
// e = exp(u), u = f*0.2-0.1, f = bits*2^-32 (<=2.4e-8 rel dev from JAX's
// (bits>>9)*2^-23 mapping; 1e5x under bf16 rounding). exp2 on trans pipe.
// Row sums accumulate in fp32 (two independent chains).
__device__ __forceinline__ short8v gen_a(uint32_t c0, float& zp0, float& zp1) {
    uint32_t r[8];
    tf8(c0, r);
    float e[8];
#pragma unroll
    for (int i = 0; i < 8; ++i) {
        const float fm = (float)r[i];                       // v_cvt_f32_u32
        e[i] = __builtin_amdgcn_exp2f(__builtin_fmaf(fm, EXP_A32, EXP_B));
    }
    zp0 += (e[0] + e[2]) + (e[4] + e[6]);
    zp1 += (e[1] + e[3]) + (e[5] + e[7]);
    union { uint32_t u[4]; short8v v; } a;
#pragma unroll
    for (int i = 0; i < 4; ++i) a.u[i] = cvt_pk_bf16(e[2 * i], e[2 * i + 1]);
    return a.v;
}

// ---- prologue: pack X^T (bf16) in B-fragment lane order (r11 verbatim) ----
// Fragment index F = ((b*64 + kt)*2 + kc)*4 + dg  (8 frags per kt contiguous).
// bf[F*512 + l*8 + j] = bf16( X[b][kt*64 + kc*32 + (l>>4)*8 + j][dg*16 + (l&15)] )
__global__ __launch_bounds__(64) void pack_xt_bf16(
    const float* __restrict__ x, short* __restrict__ bf)
{
    const int id = blockIdx.x;            // 2048 blocks
    const int l  = threadIdx.x;           // 0..63
    const int dg = id & 3;
    const int kc = (id >> 2) & 1;
    const int kt = (id >> 3) & 63;
    const int b  = id >> 9;
    const int d  = dg * 16 + (l & 15);
    const int k0 = kt * 64 + kc * 32 + (l >> 4) * 8;
    const float* __restrict__ xb = x + (size_t)b * (S_ * D_);
    union { short8v v; short s[8]; } r;
#pragma unroll
    for (int j = 0; j < 8; ++j) {
        __hip_bfloat16 h = __float2bfloat16(xb[(size_t)(k0 + j) * D_ + d]);
        r.s[j] = __builtin_bit_cast(short, h);
    }
    *(short8v*)&bf[(size_t)id * 512 + l * 8] = r.v;
}

__global__ __launch_bounds__(512, 8) void fused_rand_attn_pc(
    const short* __restrict__ bf, float* __restrict__ out)
{
    const int tid  = threadIdx.x;
    // XCD-aware swizzle (1024 % 8 == 0 -> bijective)
    const int bid  = (blockIdx.x & 7) * 128 + (blockIdx.x >> 3);
    const int b    = bid >> 8;            // batch
    const int s0   = (bid & 255) * 16;    // s-tile start
    const int w    = tid >> 6;            // waves 0-3: producers, 4-7: consumers
    const int lane = tid & 63;
    const int lt   = lane & 15;
    const int lh   = lane >> 4;

    __shared__ short Wring[8][2][512];    // 8-slot ring of A-frag pairs (16 KiB)
    __shared__ float ZL[4][16];           // per-producer row-sum partials

    // producer state
    float zp0 = 0.f, zp1 = 0.f;
    const uint32_t fbase = ((uint32_t)b << 24) | ((uint32_t)(s0 + lt) << 12)
                           | (uint32_t)(lh * 8);
    // consumer state
    floatx4 acc = {0.f, 0.f, 0.f, 0.f};
    const int dgc = (w >= 4) ? (w - 4) : 0;     // consumer d-group
    const short* __restrict__ bl =
        bf + (size_t)b * 262144 + dgc * 512 + (size_t)lane * 8;

    // Ring discipline: iter j, producers write tiles 4j+w (slots (4j+w)&7);
    // consumers read tiles 4(j-1)..4(j-1)+3 (the other slot half). One
    // barrier per iter separates write(j) from read(j+1) and read(j) from
    // the slot's next overwrite (j+1): disjoint halves each iter -> race-free.
#pragma unroll 1
    for (int j = 0; j < 16; ++j) {
        if (w < 4) {
            const int kt = 4 * j + w;
            const int sl = kt & 7;
            const uint32_t kb = fbase + ((uint32_t)kt << 6);
            const short8v a0 = gen_a(kb, zp0, zp1);
            const short8v a1 = gen_a(kb + 32u, zp0, zp1);
            *(short8v*)&Wring[sl][0][lane * 8] = a0;   // ds_write_b128, linear
            *(short8v*)&Wring[sl][1][lane * 8] = a1;
        } else if (j > 0) {
            const int kt0 = 4 * (j - 1);
#pragma unroll
            for (int q = 0; q < 4; ++q) {
                const int kt = kt0 + q;
                const short* pb = bl + (size_t)kt * 4096;
                const short8v A0 = *(const short8v*)&Wring[kt & 7][0][lane * 8];
                const short8v B0 = *(const short8v*)(pb);
                acc = __builtin_amdgcn_mfma_f32_16x16x32_bf16(A0, B0, acc, 0,0,0);
                const short8v A1 = *(const short8v*)&Wring[kt & 7][1][lane * 8];
                const short8v B1 = *(const short8v*)(pb + 2048);
                acc = __builtin_amdgcn_mfma_f32_16x16x32_bf16(A1, B1, acc, 0,0,0);
            }
        }
        __syncthreads();
    }

    if (w >= 4) {
        // tail: tiles 60..63 (produced at j=15, synced)
#pragma unroll
        for (int q = 0; q < 4; ++q) {
            const int kt = 60 + q;
            const short* pb = bl + (size_t)kt * 4096;
            const short8v A0 = *(const short8v*)&Wring[kt & 7][0][lane * 8];
            const short8v B0 = *(const short8v*)(pb);
            acc = __builtin_amdgcn_mfma_f32_16x16x32_bf16(A0, B0, acc, 0,0,0);
            const short8v A1 = *(const short8v*)&Wring[kt & 7][1][lane * 8];
            const short8v B1 = *(const short8v*)(pb + 2048);
            acc = __builtin_amdgcn_mfma_f32_16x16x32_bf16(A1, B1, acc, 0,0,0);
        }
    } else {
        // producer Z: reduce lh groups; lanes 0-15 hold rows lt
        float zp = zp0 + zp1;
        zp += __shfl_xor(zp, 16);
        zp += __shfl_xor(zp, 32);
        if (lane < 16) ZL[w][lane] = zp;
    }
    __syncthreads();

    if (w >= 4) {
        // epilogue: C layout col=lane&15 (d), row=lh*4+reg (s); scale 1/(4Z)
        const int col = dgc * 16 + lt;
#pragma unroll
        for (int r = 0; r < 4; ++r) {
            const int row = lh * 4 + r;
            const float Z = (ZL[0][row] + ZL[1][row]) + (ZL[2][row] + ZL[3][row]);
            out[((size_t)b * S_ + (s0 + row)) * D_ + col] = acc[r] * (0.25f / Z);
        }
    }
}

extern "C" void kernel_launch(void* const* d_in, const int* in_sizes, int n_in,
                              void* d_out, int out_size, void* d_ws, size_t ws_size,
                              hipStream_t stream) {
    const float* x = (const float*)d_in[0];   // [4,4096,64] fp32
    // d_in[1] (attn_mask) is dead in the reference; unused.
    float* out = (float*)d_out;               // [4,4096,64] fp32
    short* bfw = (short*)d_ws;                // 2 MiB scratch
    (void)in_sizes; (void)n_in; (void)out_size; (void)ws_size;
    // prologue: one-time X^T bf16 fragment pack (same stream -> ordered)
    hipLaunchKernelGGL(pack_xt_bf16, dim3(2048), dim3(64), 0, stream, x, bfw);
    // main: 4 batches x 256 s-tiles = 1024 blocks x 8 waves (4P + 4C)
    hipLaunchKernelGGL(fused_rand_attn_pc, dim3(1024), dim3(512), 0, stream,
                       bfw, out);
}

// Round 15
// 133.875 us; speedup vs baseline: 1.0083x; 1.0083x over previous
//
#include <hip/hip_runtime.h>
#include <hip/hip_bf16.h>
#include <stdint.h>

// out[b,s,d] = sum_t w[b,s,t] * x[b,t,d]
//   w = softmax(uniform(key=42, (4,4096,4096), -0.1, 0.1), -1) / 4   (denom
//   = sum_{b,t} softmax = B = 4 exactly; verified rounds 2-13).
// PRNG (verified): JAX partitionable threefry, counter (0, flat_idx),
// key (0,42), draw = x0 ^ x1.
// Round 15: restore round-11 source VERBATIM (last known good, 133.9 us).
// r12/r14's "algebraically equivalent" tf8 rewrites both failed validation;
// per rigor discipline they are reverted, not patched. Session conclusion:
// int-VALU throughput-bound (~16 lanes/cyc/SIMD, 4 cyc/wave64 int op);
// measured 141 us vs ~132 us pipe-model floor (~93%).

#define S_ 4096
#define D_ 64

#define EXP_A32 ((float)(0.2 * 1.4426950408889634 / 4294967296.0)) // 0.2*log2e*2^-32
#define EXP_B   ((float)(-0.1 * 1.4426950408889634))               // -0.1*log2e

typedef __attribute__((ext_vector_type(8))) short short8v;   // 8 bf16 = 4 VGPR
typedef __attribute__((ext_vector_type(4))) float floatx4;

// 8 partitionable-threefry chains, interleaved round-by-round: counters
// (0, c0+i) i=0..7, key (0,42); draw = x0 ^ x1.
__device__ __forceinline__ void tf8(uint32_t c0, uint32_t r[8]) {
    const uint32_t k1 = 42u, k2 = 0x1BD11BDAu ^ 42u;
    uint32_t a[8], b[8];
#pragma unroll
    for (int i = 0; i < 8; ++i) { a[i] = 0u; b[i] = c0 + (uint32_t)i + k1; }
#define TF_RND(rot)                                          \
    _Pragma("unroll")                                        \
    for (int i = 0; i < 8; ++i) {                            \
        a[i] += b[i];                                        \
        b[i] = __builtin_rotateleft32(b[i], (rot));          \
        b[i] ^= a[i];                                        \
    }
#define TF_INJ(ka, kb)                                       \
    _Pragma("unroll")                                        \
    for (int i = 0; i < 8; ++i) { a[i] += (ka); b[i] += (kb); }
    TF_RND(13) TF_RND(15) TF_RND(26) TF_RND(6)
    TF_INJ(k1, k2 + 1u)
    TF_RND(17) TF_RND(29) TF_RND(16) TF_RND(24)
    TF_INJ(k2, 2u)
    TF_RND(13) TF_RND(15) TF_RND(26) TF_RND(6)
    TF_INJ(0u, k1 + 3u)
    TF_RND(17) TF_RND(29) TF_RND(16) TF_RND(24)
    TF_INJ(k1, k2 + 4u)
    TF_RND(13) TF_RND(15) TF_RND(26) TF_RND(6)
    TF_INJ(k2, 5u)
#undef TF_RND
#undef TF_INJ
#pragma unroll
    for (int i = 0; i < 8; ++i) r[i] = a[i] ^ b[i];
}

// packed pair {lo: bf16(e0), hi: bf16(e1)}, RNE, single instruction
__device__ __forceinline__ uint32_t cvt_pk_bf16(float e0, float e1) {
    uint32_t r;
    asm("v_cvt_pk_bf16_f32 %0, %1, %2" : "=v"(r) : "v"(e0), "v"(e1));
    return r;
}

// 8 consecutive exp-weights (counters c0..c0+7) -> bf16x8 A-fragment.
// e = exp(u), u = f*0.2-0.1, f = bits*2^-32 (dev from JAX's (bits>>9)*2^-23
// mapping <= 2.4e-8 rel -- 1e5 x under bf16 rounding). exp on trans pipe.
__device__ __forceinline__ short8v gen_a(uint32_t c0) {
    uint32_t r[8];
    tf8(c0, r);
    float e[8];
#pragma unroll
    for (int i = 0; i < 8; ++i) {
        const float fm = (float)r[i];                       // v_cvt_f32_u32
        e[i] = __builtin_amdgcn_exp2f(__builtin_fmaf(fm, EXP_A32, EXP_B));
    }
    union { uint32_t u[4]; short8v v; } a;
#pragma unroll
    for (int i = 0; i < 4; ++i) a.u[i] = cvt_pk_bf16(e[2 * i], e[2 * i + 1]);
    return a.v;
}

// ---- prologue: pack X^T (bf16) in B-fragment lane order ----
// Fragment index F = ((b*64 + kt)*2 + kc)*4 + dg  (8 frags per kt contiguous).
// bf[F*512 + l*8 + j] = bf16( X[b][kt*64 + kc*32 + (l>>4)*8 + j][dg*16 + (l&15)] )
__global__ __launch_bounds__(64) void pack_xt_bf16(
    const float* __restrict__ x, short* __restrict__ bf)
{
    const int id = blockIdx.x;            // 2048 blocks
    const int l  = threadIdx.x;           // 0..63
    const int dg = id & 3;
    const int kc = (id >> 2) & 1;
    const int kt = (id >> 3) & 63;
    const int b  = id >> 9;
    const int d  = dg * 16 + (l & 15);
    const int k0 = kt * 64 + kc * 32 + (l >> 4) * 8;
    const float* __restrict__ xb = x + (size_t)b * (S_ * D_);
    union { short8v v; short s[8]; } r;
#pragma unroll
    for (int j = 0; j < 8; ++j) {
        __hip_bfloat16 h = __float2bfloat16(xb[(size_t)(k0 + j) * D_ + d]);
        r.s[j] = __builtin_bit_cast(short, h);
    }
    *(short8v*)&bf[(size_t)id * 512 + l * 8] = r.v;
}

__global__ __launch_bounds__(512, 4) void fused_rand_attn_mfma5(
    const short* __restrict__ bf, float* __restrict__ out)
{
    const int tid  = threadIdx.x;
    // XCD-aware swizzle (1024 % 8 == 0 -> bijective)
    const int bid  = (blockIdx.x & 7) * 128 + (blockIdx.x >> 3);
    const int b    = bid >> 8;            // batch
    const int s0   = (bid & 255) * 16;    // s-tile start
    const int w    = tid >> 6;            // wave 0..7: k-tiles kt = w, w+8, ...
    const int lane = tid & 63;
    const int lt   = lane & 15;
    const int lh   = lane >> 4;

    __shared__ float ACC[8][4][64][4];    // [wave][dgroup][lane][reg]  32 KiB
    __shared__ float ZL[8][16];           // [wave][row]

    floatx4 acc0 = {0.f,0.f,0.f,0.f}, acc1 = {0.f,0.f,0.f,0.f};
    floatx4 acc2 = {0.f,0.f,0.f,0.f}, acc3 = {0.f,0.f,0.f,0.f};
    floatx4 accz = {0.f,0.f,0.f,0.f};     // row sums via ones-fragment MFMA

    const short one_bf = (short)0x3F80;   // bf16 1.0
    const short8v bones = {one_bf, one_bf, one_bf, one_bf,
                           one_bf, one_bf, one_bf, one_bf};

    // per-lane base into the fragment pack (frags for kt are 4096 elems apart)
    const short* __restrict__ bl =
        bf + (size_t)b * (64 * 4096) + (size_t)lane * 8;
    const uint32_t fl = (((uint32_t)b << 24) | ((uint32_t)(s0 + lt) << 12))
                        + (uint32_t)(lh * 8);

#pragma unroll 1
    for (int kt = w; kt < 64; kt += 8) {
        const short* pk = bl + (size_t)kt * 4096;
        const uint32_t kb = fl + ((uint32_t)kt << 6);

        // all 8 B fragments issued up front (L2-resident; gen covers latency)
        const short8v b00 = *(const short8v*)(pk);
        const short8v b10 = *(const short8v*)(pk + 512);
        const short8v b20 = *(const short8v*)(pk + 1024);
        const short8v b30 = *(const short8v*)(pk + 1536);
        const short8v b01 = *(const short8v*)(pk + 2048);
        const short8v b11 = *(const short8v*)(pk + 2560);
        const short8v b21 = *(const short8v*)(pk + 3072);
        const short8v b31 = *(const short8v*)(pk + 3584);

        // A fragments: 16 threefry chains total, explicitly interleaved
        const short8v a0 = gen_a(kb);
        const short8v a1 = gen_a(kb + 32u);

        acc0 = __builtin_amdgcn_mfma_f32_16x16x32_bf16(a0, b00, acc0, 0, 0, 0);
        acc1 = __builtin_amdgcn_mfma_f32_16x16x32_bf16(a0, b10, acc1, 0, 0, 0);
        acc2 = __builtin_amdgcn_mfma_f32_16x16x32_bf16(a0, b20, acc2, 0, 0, 0);
        acc3 = __builtin_amdgcn_mfma_f32_16x16x32_bf16(a0, b30, acc3, 0, 0, 0);
        accz = __builtin_amdgcn_mfma_f32_16x16x32_bf16(a0, bones, accz, 0, 0, 0);
        acc0 = __builtin_amdgcn_mfma_f32_16x16x32_bf16(a1, b01, acc0, 0, 0, 0);
        acc1 = __builtin_amdgcn_mfma_f32_16x16x32_bf16(a1, b11, acc1, 0, 0, 0);
        acc2 = __builtin_amdgcn_mfma_f32_16x16x32_bf16(a1, b21, acc2, 0, 0, 0);
        acc3 = __builtin_amdgcn_mfma_f32_16x16x32_bf16(a1, b31, acc3, 0, 0, 0);
        accz = __builtin_amdgcn_mfma_f32_16x16x32_bf16(a1, bones, accz, 0, 0, 0);
    }

    // ---- stash this wave's partials ----
    // accz[r] = partial Z of row lh*4+r (all 16 cols identical; lt==0 writes)
    if (lt == 0) {
#pragma unroll
        for (int r = 0; r < 4; ++r) ZL[w][lh * 4 + r] = accz[r];
    }
    *(floatx4*)&ACC[w][0][lane][0] = acc0;
    *(floatx4*)&ACC[w][1][lane][0] = acc1;
    *(floatx4*)&ACC[w][2][lane][0] = acc2;
    *(floatx4*)&ACC[w][3][lane][0] = acc3;
    __syncthreads();                      // the only barrier in the kernel

    // ---- wave w: d-group w&3, row-half w>>2 (2 rows/thread) ----
    const int dg = w & 3;
    const int rh = w >> 2;
    floatx4 facc = {0.f,0.f,0.f,0.f};
#pragma unroll
    for (int w2 = 0; w2 < 8; ++w2) {
        const floatx4 t = *(const floatx4*)&ACC[w2][dg][lane][0];
        facc.x += t.x; facc.y += t.y; facc.z += t.z; facc.w += t.w;
    }
    // static selects (no dynamic vector index -> no scratch)
    const float v0 = rh ? facc.z : facc.x;
    const float v1 = rh ? facc.w : facc.y;
    const int row0 = lh * 4 + rh * 2;     // C layout: col=lane&15, row=lh*4+reg
    float Z0 = 0.f, Z1 = 0.f;
#pragma unroll
    for (int w2 = 0; w2 < 8; ++w2) {
        Z0 += ZL[w2][row0];
        Z1 += ZL[w2][row0 + 1];
    }
    const int col = dg * 16 + lt;
    out[((size_t)b * S_ + (s0 + row0)) * D_ + col]     = v0 * (0.25f / Z0);
    out[((size_t)b * S_ + (s0 + row0 + 1)) * D_ + col] = v1 * (0.25f / Z1);
}

extern "C" void kernel_launch(void* const* d_in, const int* in_sizes, int n_in,
                              void* d_out, int out_size, void* d_ws, size_t ws_size,
                              hipStream_t stream) {
    const float* x = (const float*)d_in[0];   // [4,4096,64] fp32
    // d_in[1] (attn_mask) is dead in the reference; unused.
    float* out = (float*)d_out;               // [4,4096,64] fp32
    short* bfw = (short*)d_ws;                // 2 MiB scratch
    (void)in_sizes; (void)n_in; (void)out_size; (void)ws_size;
    // prologue: one-time X^T bf16 fragment pack (same stream -> ordered)
    hipLaunchKernelGGL(pack_xt_bf16, dim3(2048), dim3(64), 0, stream, x, bfw);
    // main: 4 batches x 256 s-tiles = 1024 blocks x 8 waves (512 threads)
    hipLaunchKernelGGL(fused_rand_attn_mfma5, dim3(1024), dim3(512), 0, stream,
                       bfw, out);
}

// Round 16
// 133.803 us; speedup vs baseline: 1.0089x; 1.0005x over previous
//
#include <hip/hip_runtime.h>
#include <hip/hip_bf16.h>
#include <stdint.h>

// out[b,s,d] = sum_t w[b,s,t] * x[b,t,d]
//   w = softmax(uniform(key=42, (4,4096,4096), -0.1, 0.1), -1) / 4   (denom
//   = sum_{b,t} softmax = B = 4 exactly; verified rounds 2-13).
// PRNG (verified): JAX partitionable threefry, counter (0, flat_idx),
// key (0,42), draw = x0 ^ x1.
// Round 15: restore round-11 source VERBATIM (last known good, 133.9 us).
// r12/r14's "algebraically equivalent" tf8 rewrites both failed validation;
// per rigor discipline they are reverted, not patched. Session conclusion:
// int-VALU throughput-bound (~16 lanes/cyc/SIMD, 4 cyc/wave64 int op);
// measured 141 us vs ~132 us pipe-model floor (~93%).

#define S_ 4096
#define D_ 64

#define EXP_A32 ((float)(0.2 * 1.4426950408889634 / 4294967296.0)) // 0.2*log2e*2^-32
#define EXP_B   ((float)(-0.1 * 1.4426950408889634))               // -0.1*log2e

typedef __attribute__((ext_vector_type(8))) short short8v;   // 8 bf16 = 4 VGPR
typedef __attribute__((ext_vector_type(4))) float floatx4;

// 8 partitionable-threefry chains, interleaved round-by-round: counters
// (0, c0+i) i=0..7, key (0,42); draw = x0 ^ x1.
__device__ __forceinline__ void tf8(uint32_t c0, uint32_t r[8]) {
    const uint32_t k1 = 42u, k2 = 0x1BD11BDAu ^ 42u;
    uint32_t a[8], b[8];
#pragma unroll
    for (int i = 0; i < 8; ++i) { a[i] = 0u; b[i] = c0 + (uint32_t)i + k1; }
#define TF_RND(rot)                                          \
    _Pragma("unroll")                                        \
    for (int i = 0; i < 8; ++i) {                            \
        a[i] += b[i];                                        \
        b[i] = __builtin_rotateleft32(b[i], (rot));          \
        b[i] ^= a[i];                                        \
    }
#define TF_INJ(ka, kb)                                       \
    _Pragma("unroll")                                        \
    for (int i = 0; i < 8; ++i) { a[i] += (ka); b[i] += (kb); }
    TF_RND(13) TF_RND(15) TF_RND(26) TF_RND(6)
    TF_INJ(k1, k2 + 1u)
    TF_RND(17) TF_RND(29) TF_RND(16) TF_RND(24)
    TF_INJ(k2, 2u)
    TF_RND(13) TF_RND(15) TF_RND(26) TF_RND(6)
    TF_INJ(0u, k1 + 3u)
    TF_RND(17) TF_RND(29) TF_RND(16) TF_RND(24)
    TF_INJ(k1, k2 + 4u)
    TF_RND(13) TF_RND(15) TF_RND(26) TF_RND(6)
    TF_INJ(k2, 5u)
#undef TF_RND
#undef TF_INJ
#pragma unroll
    for (int i = 0; i < 8; ++i) r[i] = a[i] ^ b[i];
}

// packed pair {lo: bf16(e0), hi: bf16(e1)}, RNE, single instruction
__device__ __forceinline__ uint32_t cvt_pk_bf16(float e0, float e1) {
    uint32_t r;
    asm("v_cvt_pk_bf16_f32 %0, %1, %2" : "=v"(r) : "v"(e0), "v"(e1));
    return r;
}

// 8 consecutive exp-weights (counters c0..c0+7) -> bf16x8 A-fragment.
// e = exp(u), u = f*0.2-0.1, f = bits*2^-32 (dev from JAX's (bits>>9)*2^-23
// mapping <= 2.4e-8 rel -- 1e5 x under bf16 rounding). exp on trans pipe.
__device__ __forceinline__ short8v gen_a(uint32_t c0) {
    uint32_t r[8];
    tf8(c0, r);
    float e[8];
#pragma unroll
    for (int i = 0; i < 8; ++i) {
        const float fm = (float)r[i];                       // v_cvt_f32_u32
        e[i] = __builtin_amdgcn_exp2f(__builtin_fmaf(fm, EXP_A32, EXP_B));
    }
    union { uint32_t u[4]; short8v v; } a;
#pragma unroll
    for (int i = 0; i < 4; ++i) a.u[i] = cvt_pk_bf16(e[2 * i], e[2 * i + 1]);
    return a.v;
}

// ---- prologue: pack X^T (bf16) in B-fragment lane order ----
// Fragment index F = ((b*64 + kt)*2 + kc)*4 + dg  (8 frags per kt contiguous).
// bf[F*512 + l*8 + j] = bf16( X[b][kt*64 + kc*32 + (l>>4)*8 + j][dg*16 + (l&15)] )
__global__ __launch_bounds__(64) void pack_xt_bf16(
    const float* __restrict__ x, short* __restrict__ bf)
{
    const int id = blockIdx.x;            // 2048 blocks
    const int l  = threadIdx.x;           // 0..63
    const int dg = id & 3;
    const int kc = (id >> 2) & 1;
    const int kt = (id >> 3) & 63;
    const int b  = id >> 9;
    const int d  = dg * 16 + (l & 15);
    const int k0 = kt * 64 + kc * 32 + (l >> 4) * 8;
    const float* __restrict__ xb = x + (size_t)b * (S_ * D_);
    union { short8v v; short s[8]; } r;
#pragma unroll
    for (int j = 0; j < 8; ++j) {
        __hip_bfloat16 h = __float2bfloat16(xb[(size_t)(k0 + j) * D_ + d]);
        r.s[j] = __builtin_bit_cast(short, h);
    }
    *(short8v*)&bf[(size_t)id * 512 + l * 8] = r.v;
}

__global__ __launch_bounds__(512, 4) void fused_rand_attn_mfma5(
    const short* __restrict__ bf, float* __restrict__ out)
{
    const int tid  = threadIdx.x;
    // XCD-aware swizzle (1024 % 8 == 0 -> bijective)
    const int bid  = (blockIdx.x & 7) * 128 + (blockIdx.x >> 3);
    const int b    = bid >> 8;            // batch
    const int s0   = (bid & 255) * 16;    // s-tile start
    const int w    = tid >> 6;            // wave 0..7: k-tiles kt = w, w+8, ...
    const int lane = tid & 63;
    const int lt   = lane & 15;
    const int lh   = lane >> 4;

    __shared__ float ACC[8][4][64][4];    // [wave][dgroup][lane][reg]  32 KiB
    __shared__ float ZL[8][16];           // [wave][row]

    floatx4 acc0 = {0.f,0.f,0.f,0.f}, acc1 = {0.f,0.f,0.f,0.f};
    floatx4 acc2 = {0.f,0.f,0.f,0.f}, acc3 = {0.f,0.f,0.f,0.f};
    floatx4 accz = {0.f,0.f,0.f,0.f};     // row sums via ones-fragment MFMA

    const short one_bf = (short)0x3F80;   // bf16 1.0
    const short8v bones = {one_bf, one_bf, one_bf, one_bf,
                           one_bf, one_bf, one_bf, one_bf};

    // per-lane base into the fragment pack (frags for kt are 4096 elems apart)
    const short* __restrict__ bl =
        bf + (size_t)b * (64 * 4096) + (size_t)lane * 8;
    const uint32_t fl = (((uint32_t)b << 24) | ((uint32_t)(s0 + lt) << 12))
                        + (uint32_t)(lh * 8);

#pragma unroll 1
    for (int kt = w; kt < 64; kt += 8) {
        const short* pk = bl + (size_t)kt * 4096;
        const uint32_t kb = fl + ((uint32_t)kt << 6);

        // all 8 B fragments issued up front (L2-resident; gen covers latency)
        const short8v b00 = *(const short8v*)(pk);
        const short8v b10 = *(const short8v*)(pk + 512);
        const short8v b20 = *(const short8v*)(pk + 1024);
        const short8v b30 = *(const short8v*)(pk + 1536);
        const short8v b01 = *(const short8v*)(pk + 2048);
        const short8v b11 = *(const short8v*)(pk + 2560);
        const short8v b21 = *(const short8v*)(pk + 3072);
        const short8v b31 = *(const short8v*)(pk + 3584);

        // A fragments: 16 threefry chains total, explicitly interleaved
        const short8v a0 = gen_a(kb);
        const short8v a1 = gen_a(kb + 32u);

        acc0 = __builtin_amdgcn_mfma_f32_16x16x32_bf16(a0, b00, acc0, 0, 0, 0);
        acc1 = __builtin_amdgcn_mfma_f32_16x16x32_bf16(a0, b10, acc1, 0, 0, 0);
        acc2 = __builtin_amdgcn_mfma_f32_16x16x32_bf16(a0, b20, acc2, 0, 0, 0);
        acc3 = __builtin_amdgcn_mfma_f32_16x16x32_bf16(a0, b30, acc3, 0, 0, 0);
        accz = __builtin_amdgcn_mfma_f32_16x16x32_bf16(a0, bones, accz, 0, 0, 0);
        acc0 = __builtin_amdgcn_mfma_f32_16x16x32_bf16(a1, b01, acc0, 0, 0, 0);
        acc1 = __builtin_amdgcn_mfma_f32_16x16x32_bf16(a1, b11, acc1, 0, 0, 0);
        acc2 = __builtin_amdgcn_mfma_f32_16x16x32_bf16(a1, b21, acc2, 0, 0, 0);
        acc3 = __builtin_amdgcn_mfma_f32_16x16x32_bf16(a1, b31, acc3, 0, 0, 0);
        accz = __builtin_amdgcn_mfma_f32_16x16x32_bf16(a1, bones, accz, 0, 0, 0);
    }

    // ---- stash this wave's partials ----
    // accz[r] = partial Z of row lh*4+r (all 16 cols identical; lt==0 writes)
    if (lt == 0) {
#pragma unroll
        for (int r = 0; r < 4; ++r) ZL[w][lh * 4 + r] = accz[r];
    }
    *(floatx4*)&ACC[w][0][lane][0] = acc0;
    *(floatx4*)&ACC[w][1][lane][0] = acc1;
    *(floatx4*)&ACC[w][2][lane][0] = acc2;
    *(floatx4*)&ACC[w][3][lane][0] = acc3;
    __syncthreads();                      // the only barrier in the kernel

    // ---- wave w: d-group w&3, row-half w>>2 (2 rows/thread) ----
    const int dg = w & 3;
    const int rh = w >> 2;
    floatx4 facc = {0.f,0.f,0.f,0.f};
#pragma unroll
    for (int w2 = 0; w2 < 8; ++w2) {
        const floatx4 t = *(const floatx4*)&ACC[w2][dg][lane][0];
        facc.x += t.x; facc.y += t.y; facc.z += t.z; facc.w += t.w;
    }
    // static selects (no dynamic vector index -> no scratch)
    const float v0 = rh ? facc.z : facc.x;
    const float v1 = rh ? facc.w : facc.y;
    const int row0 = lh * 4 + rh * 2;     // C layout: col=lane&15, row=lh*4+reg
    float Z0 = 0.f, Z1 = 0.f;
#pragma unroll
    for (int w2 = 0; w2 < 8; ++w2) {
        Z0 += ZL[w2][row0];
        Z1 += ZL[w2][row0 + 1];
    }
    const int col = dg * 16 + lt;
    out[((size_t)b * S_ + (s0 + row0)) * D_ + col]     = v0 * (0.25f / Z0);
    out[((size_t)b * S_ + (s0 + row0 + 1)) * D_ + col] = v1 * (0.25f / Z1);
}

extern "C" void kernel_launch(void* const* d_in, const int* in_sizes, int n_in,
                              void* d_out, int out_size, void* d_ws, size_t ws_size,
                              hipStream_t stream) {
    const float* x = (const float*)d_in[0];   // [4,4096,64] fp32
    // d_in[1] (attn_mask) is dead in the reference; unused.
    float* out = (float*)d_out;               // [4,4096,64] fp32
    short* bfw = (short*)d_ws;                // 2 MiB scratch
    (void)in_sizes; (void)n_in; (void)out_size; (void)ws_size;
    // prologue: one-time X^T bf16 fragment pack (same stream -> ordered)
    hipLaunchKernelGGL(pack_xt_bf16, dim3(2048), dim3(64), 0, stream, x, bfw);
    // main: 4 batches x 256 s-tiles = 1024 blocks x 8 waves (512 threads)
    hipLaunchKernelGGL(fused_rand_attn_mfma5, dim3(1024), dim3(512), 0, stream,
                       bfw, out);
}